// Round 1
// baseline (2538.118 us; speedup 1.0000x reference)
//
#include <hip/hip_runtime.h>
#include <math.h>

#define BB 4
#define CQ 384
#define CKD 384
#define CO 384
#define NN 2048
#define KK 16
#define GG 32
#define CPG 12          // CO / GG
#define EPSV 1e-5f
#define SCALE 0.05103103630798288f   // 1/sqrt(384)

// ws layout (floats):
//   [0,256)            stats: per (b,g) {sum, sumsq}
//   [256, 256+3072)    ab:    per (b,o) {alpha, beta2}  (beta2 folds bv)
//   [3328, 3328+131072) p:    softmax probs per (b,n,k)
#define WS_STATS 0
#define WS_AB    256
#define WS_P     3328

__global__ __launch_bounds__(384) void k_qscore_stats(
    const float* __restrict__ feat, const float* __restrict__ gf,
    const int* __restrict__ count,
    const float* __restrict__ Wq, const float* __restrict__ bq,
    const float* __restrict__ Wk, const float* __restrict__ bk,
    const float* __restrict__ Wv, const float* __restrict__ bv,
    float* __restrict__ stats, float* __restrict__ p_out)
{
    const int bid = blockIdx.x;
    const int b = bid >> 11;          // / 2048
    const int n = bid & (NN - 1);
    const int tid = threadIdx.x;

    __shared__ float sf[CQ];
    __shared__ float sq[CO];
    __shared__ float su[CKD];
    __shared__ float sg[CKD * KK];    // 24 KB, layout [c][k]
    __shared__ float red1[CO];
    __shared__ float red2[CO];
    __shared__ float sp[KK];
    __shared__ float s_qb;

    // ---- stage feat column (stride-N gather) ----
    sf[tid] = feat[(size_t)b * CQ * NN + (size_t)tid * NN + n];

    // ---- stage grouped_feat tile [384 x 16] ----
    {
        const float4* gf4 = reinterpret_cast<const float4*>(
            gf + (size_t)b * CKD * NN * KK + (size_t)n * KK);
        float4* sg4 = reinterpret_cast<float4*>(sg);
        #pragma unroll
        for (int idx = tid; idx < CKD * 4; idx += 384) {
            int c = idx >> 2, j = idx & 3;
            sg4[idx] = gf4[(size_t)c * (NN * KK / 4) + j];
        }
    }
    __syncthreads();

    // ---- q[o] = bq[o] + feat_col . Wq[o,:] ----
    float qo = bq[tid];
    {
        const float4* wq4 = reinterpret_cast<const float4*>(Wq + (size_t)tid * CQ);
        const float4* sf4 = reinterpret_cast<const float4*>(sf);
        #pragma unroll 8
        for (int c4 = 0; c4 < CQ / 4; ++c4) {
            float4 w = wq4[c4]; float4 f = sf4[c4];
            qo = fmaf(w.x, f.x, qo); qo = fmaf(w.y, f.y, qo);
            qo = fmaf(w.z, f.z, qo); qo = fmaf(w.w, f.w, qo);
        }
    }
    sq[tid] = qo;
    red1[tid] = qo * bk[tid];
    __syncthreads();

    // ---- reduce qb = q . bk ----
    for (int s = 192; s > 1; s >>= 1) {
        if (tid < s) red1[tid] += red1[tid + s];
        __syncthreads();
    }
    if (tid == 0) s_qb = red1[0] + red1[1] + red1[2];
    __syncthreads();

    // ---- u[c] = sum_o q[o] * Wk[o,c]  (coalesced across threads) ----
    {
        float uc = 0.f;
        #pragma unroll 8
        for (int o = 0; o < CO; ++o)
            uc = fmaf(sq[o], Wk[(size_t)o * CKD + tid], uc);
        su[tid] = uc;
    }
    __syncthreads();

    // ---- scores partials: thread = (k = tid&15, chunk = tid>>4 of 24) ----
    {
        int k = tid & 15, ch = tid >> 4;
        float part = 0.f;
        #pragma unroll
        for (int c = ch * 16; c < ch * 16 + 16; ++c)
            part = fmaf(su[c], sg[(c << 4) + k], part);
        red2[tid] = part;
    }
    __syncthreads();
    if (tid < KK) {
        float s = 0.f;
        #pragma unroll
        for (int j = 0; j < 24; ++j) s += red2[tid + 16 * j];
        sp[tid] = (s + s_qb) * SCALE;
    }
    __syncthreads();

    // ---- masked softmax over k (thread 0, tiny) ----
    if (tid == 0) {
        int cnt = count[b * NN + n];
        if (cnt < 1) cnt = 1; if (cnt > KK) cnt = KK;
        float m = -1e30f;
        for (int k = 0; k < cnt; ++k) m = fmaxf(m, sp[k]);
        float ssum = 0.f;
        float e[KK];
        for (int k = 0; k < KK; ++k) {
            e[k] = (k < cnt) ? expf(sp[k] - m) : 0.f;
            ssum += e[k];
        }
        float inv = 1.f / ssum;
        for (int k = 0; k < KK; ++k)
            p_out[((size_t)b * NN + n) * KK + k] = e[k] * inv;
    }

    // ---- v_raw[o, 0..15] + GroupNorm stats ----
    float acc[KK];
    #pragma unroll
    for (int k = 0; k < KK; ++k) acc[k] = 0.f;
    {
        const float* wv = Wv + (size_t)tid * CKD;
        for (int c = 0; c < CKD; ++c) {
            float w = wv[c];
            const float4* row = reinterpret_cast<const float4*>(sg + (c << 4));
            float4 a0 = row[0], a1 = row[1], a2 = row[2], a3 = row[3];
            acc[0]  = fmaf(w, a0.x, acc[0]);  acc[1]  = fmaf(w, a0.y, acc[1]);
            acc[2]  = fmaf(w, a0.z, acc[2]);  acc[3]  = fmaf(w, a0.w, acc[3]);
            acc[4]  = fmaf(w, a1.x, acc[4]);  acc[5]  = fmaf(w, a1.y, acc[5]);
            acc[6]  = fmaf(w, a1.z, acc[6]);  acc[7]  = fmaf(w, a1.w, acc[7]);
            acc[8]  = fmaf(w, a2.x, acc[8]);  acc[9]  = fmaf(w, a2.y, acc[9]);
            acc[10] = fmaf(w, a2.z, acc[10]); acc[11] = fmaf(w, a2.w, acc[11]);
            acc[12] = fmaf(w, a3.x, acc[12]); acc[13] = fmaf(w, a3.y, acc[13]);
            acc[14] = fmaf(w, a3.z, acc[14]); acc[15] = fmaf(w, a3.w, acc[15]);
        }
    }
    {
        float bvo = bv[tid];
        float s1 = 0.f, s2 = 0.f;
        #pragma unroll
        for (int k = 0; k < KK; ++k) {
            float v = acc[k] + bvo;
            s1 += v; s2 = fmaf(v, v, s2);
        }
        __syncthreads();          // red1/red2 free for reuse
        red1[tid] = s1; red2[tid] = s2;
    }
    __syncthreads();
    if (tid < GG) {
        float a1 = 0.f, a2 = 0.f;
        #pragma unroll
        for (int j = 0; j < CPG; ++j) {
            a1 += red1[tid * CPG + j];
            a2 += red2[tid * CPG + j];
        }
        atomicAdd(&stats[(b * GG + tid) * 2 + 0], a1);
        atomicAdd(&stats[(b * GG + tid) * 2 + 1], a2);
    }
}

__global__ __launch_bounds__(384) void k_stats_final(
    const float* __restrict__ stats,
    const float* __restrict__ gn_w, const float* __restrict__ gn_b,
    const float* __restrict__ bv, float* __restrict__ ab)
{
    __shared__ float smu[BB * GG], srs[BB * GG];
    int tid = threadIdx.x;
    if (tid < BB * GG) {
        float s1 = stats[tid * 2], s2 = stats[tid * 2 + 1];
        const float cnt = (float)(CPG * NN * KK);
        float mu = s1 / cnt;
        float var = s2 / cnt - mu * mu;
        smu[tid] = mu;
        srs[tid] = rsqrtf(var + EPSV);
    }
    __syncthreads();
    for (int i = tid; i < BB * CO; i += 384) {
        int b = i / CO, o = i % CO;
        int g = o / CPG;
        float rs = srs[b * GG + g], mu = smu[b * GG + g];
        float a = rs * gn_w[o];
        float be = gn_b[o] - mu * a + a * bv[o];   // folds bv into beta
        ab[i * 2] = a;
        ab[i * 2 + 1] = be;
    }
}

__global__ __launch_bounds__(384) void k_out(
    const float* __restrict__ gf, const float* __restrict__ Wv,
    const float* __restrict__ ab, const float* __restrict__ p_in,
    float* __restrict__ out)
{
    const int bid = blockIdx.x;
    const int b = bid >> 11;
    const int n = bid & (NN - 1);
    const int tid = threadIdx.x;

    __shared__ float sg[CKD * KK];
    __shared__ float sp[KK];

    {
        const float4* gf4 = reinterpret_cast<const float4*>(
            gf + (size_t)b * CKD * NN * KK + (size_t)n * KK);
        float4* sg4 = reinterpret_cast<float4*>(sg);
        #pragma unroll
        for (int idx = tid; idx < CKD * 4; idx += 384) {
            int c = idx >> 2, j = idx & 3;
            sg4[idx] = gf4[(size_t)c * (NN * KK / 4) + j];
        }
    }
    if (tid < KK) sp[tid] = p_in[((size_t)b * NN + n) * KK + tid];
    __syncthreads();

    float acc[KK];
    #pragma unroll
    for (int k = 0; k < KK; ++k) acc[k] = 0.f;
    {
        const float* wv = Wv + (size_t)tid * CKD;
        for (int c = 0; c < CKD; ++c) {
            float w = wv[c];
            const float4* row = reinterpret_cast<const float4*>(sg + (c << 4));
            float4 a0 = row[0], a1 = row[1], a2 = row[2], a3 = row[3];
            acc[0]  = fmaf(w, a0.x, acc[0]);  acc[1]  = fmaf(w, a0.y, acc[1]);
            acc[2]  = fmaf(w, a0.z, acc[2]);  acc[3]  = fmaf(w, a0.w, acc[3]);
            acc[4]  = fmaf(w, a1.x, acc[4]);  acc[5]  = fmaf(w, a1.y, acc[5]);
            acc[6]  = fmaf(w, a1.z, acc[6]);  acc[7]  = fmaf(w, a1.w, acc[7]);
            acc[8]  = fmaf(w, a2.x, acc[8]);  acc[9]  = fmaf(w, a2.y, acc[9]);
            acc[10] = fmaf(w, a2.z, acc[10]); acc[11] = fmaf(w, a2.w, acc[11]);
            acc[12] = fmaf(w, a3.x, acc[12]); acc[13] = fmaf(w, a3.y, acc[13]);
            acc[14] = fmaf(w, a3.z, acc[14]); acc[15] = fmaf(w, a3.w, acc[15]);
        }
    }
    const float a  = ab[((size_t)b * CO + tid) * 2];
    const float be = ab[((size_t)b * CO + tid) * 2 + 1];
    float ov = 0.f;
    #pragma unroll
    for (int k = 0; k < KK; ++k) {
        float vn = fmaf(a, acc[k], be);
        vn = fmaxf(vn, 0.f);
        ov = fmaf(sp[k], vn, ov);
    }
    out[(size_t)b * CO * NN + (size_t)tid * NN + n] = 16.f * ov;
}

extern "C" void kernel_launch(void* const* d_in, const int* in_sizes, int n_in,
                              void* d_out, int out_size, void* d_ws, size_t ws_size,
                              hipStream_t stream) {
    const float* feat = (const float*)d_in[0];
    const float* gf   = (const float*)d_in[1];
    const int*   cnt  = (const int*)d_in[2];
    const float* Wq   = (const float*)d_in[3];
    const float* bq   = (const float*)d_in[4];
    const float* Wk   = (const float*)d_in[5];
    const float* bk   = (const float*)d_in[6];
    const float* Wv   = (const float*)d_in[7];
    const float* bv   = (const float*)d_in[8];
    const float* gnw  = (const float*)d_in[9];
    const float* gnb  = (const float*)d_in[10];
    float* out = (float*)d_out;
    float* ws  = (float*)d_ws;

    float* stats = ws + WS_STATS;
    float* ab    = ws + WS_AB;
    float* p     = ws + WS_P;

    hipMemsetAsync(stats, 0, 256 * sizeof(float), stream);
    k_qscore_stats<<<BB * NN, 384, 0, stream>>>(feat, gf, cnt, Wq, bq, Wk, bk,
                                                Wv, bv, stats, p);
    k_stats_final<<<1, 384, 0, stream>>>(stats, gnw, gnb, bv, ab);
    k_out<<<BB * NN, 384, 0, stream>>>(gf, Wv, ab, p, out);
}

// Round 2
// 447.612 us; speedup vs baseline: 5.6704x; 5.6704x over previous
//
#include <hip/hip_runtime.h>
#include <math.h>

#define BB 4
#define CC 384
#define NN 2048
#define KK 16
#define GG 32
#define CPG 12
#define MM 32768          // NN*KK
#define EPSV 1e-5f
#define SCALE 0.05103103630798288f   // 1/sqrt(384)

typedef unsigned short bf16_t;
typedef __attribute__((ext_vector_type(8))) short short8v;
typedef __attribute__((ext_vector_type(8))) unsigned short ushort8v;
typedef __attribute__((ext_vector_type(4))) unsigned short ushort4v;
typedef __attribute__((ext_vector_type(4))) float f32x4;
typedef __attribute__((ext_vector_type(4))) int int4v;

__device__ __forceinline__ unsigned short f2bf(float f) {
    unsigned u = __float_as_uint(f);
    u += 0x7fffu + ((u >> 16) & 1u);
    return (unsigned short)(u >> 16);
}
__device__ __forceinline__ float bf2f(unsigned short h) {
    return __uint_as_float(((unsigned)h) << 16);
}

// ---------------------------------------------------------------------------
// Shared 128x128x384 bf16 MFMA GEMM core. A,B: row-major bf16, 384 elems/row,
// row 0 = tile origin. acc[mf][nf] over 16x16 frags; D row=(lane>>4)*4+r,
// col=lane&15 (m89-verified layout). LDS rows 64B, slot-XOR swizzled.
// ---------------------------------------------------------------------------
__device__ __forceinline__ void gemm128(const bf16_t* __restrict__ A,
                                        const bf16_t* __restrict__ B,
                                        bf16_t* sA, bf16_t* sB,
                                        f32x4 acc[4][4])
{
    const int tid = threadIdx.x;
    const int lane = tid & 63;
    const int w = tid >> 6;
    const int wr = w >> 1, wc = w & 1;

    const int mrow = tid >> 2, slot = tid & 3;         // staging chunk
    const int srcOff = mrow * CC + slot * 8;           // + ks*32
    const int dstOff = mrow * 32 + ((slot ^ ((mrow >> 1) & 3)) * 8);

    int4v ra0, ra1, rb0, rb1;
    ra0 = *(const int4v*)(A + srcOff);
    ra1 = *(const int4v*)(A + srcOff + 64 * CC);
    rb0 = *(const int4v*)(B + srcOff);
    rb1 = *(const int4v*)(B + srcOff + 64 * CC);
    *(int4v*)(sA + dstOff) = ra0; *(int4v*)(sA + dstOff + 2048) = ra1;
    *(int4v*)(sB + dstOff) = rb0; *(int4v*)(sB + dstOff + 2048) = rb1;
    __syncthreads();

    const int fr = lane & 15, fs = lane >> 4;
    const int rdsw = (fs ^ ((fr >> 1) & 3)) * 8;
    const int aoff = (wr * 64 + fr) * 32 + rdsw;
    const int boff = (wc * 64 + fr) * 32 + rdsw;

    for (int ks = 0; ks < 12; ++ks) {
        if (ks < 11) {
            int so = srcOff + (ks + 1) * 32;
            ra0 = *(const int4v*)(A + so);
            ra1 = *(const int4v*)(A + so + 64 * CC);
            rb0 = *(const int4v*)(B + so);
            rb1 = *(const int4v*)(B + so + 64 * CC);
        }
        short8v af[4], bfv[4];
        #pragma unroll
        for (int i = 0; i < 4; ++i) {
            af[i]  = *(const short8v*)(sA + aoff + i * 16 * 32);
            bfv[i] = *(const short8v*)(sB + boff + i * 16 * 32);
        }
        #pragma unroll
        for (int mf = 0; mf < 4; ++mf)
            #pragma unroll
            for (int nf = 0; nf < 4; ++nf)
                acc[mf][nf] = __builtin_amdgcn_mfma_f32_16x16x32_bf16(
                    af[mf], bfv[nf], acc[mf][nf], 0, 0, 0);
        if (ks < 11) {
            __syncthreads();
            *(int4v*)(sA + dstOff) = ra0; *(int4v*)(sA + dstOff + 2048) = ra1;
            *(int4v*)(sB + dstOff) = rb0; *(int4v*)(sB + dstOff + 2048) = rb1;
            __syncthreads();
        }
    }
}

// ---------------------------------------------------------------------------
// k_prep: Mmat = Wk^T Wq (bf16), mb = Wk^T bq, w2 = Wq^T bk, s0 = bq.bk
// ---------------------------------------------------------------------------
__global__ __launch_bounds__(384) void k_prep(
    const float* __restrict__ Wq, const float* __restrict__ Wk,
    const float* __restrict__ bq, const float* __restrict__ bk,
    bf16_t* __restrict__ MmatB, float* __restrict__ w2,
    float* __restrict__ s0, float* __restrict__ mb)
{
    const int t = threadIdx.x, bid = blockIdx.x;
    if (bid < CC) {
        const int c = bid;
        float acc = 0.f, acc2 = 0.f;
        for (int o = 0; o < CC; ++o) {
            float wk = Wk[o * CC + c];
            acc  = fmaf(wk, Wq[o * CC + t], acc);
            acc2 = fmaf(wk, bq[o], acc2);
        }
        MmatB[c * CC + t] = f2bf(acc);
        if (t == 0) mb[c] = acc2;
    } else {
        float a = 0.f;
        for (int o = 0; o < CC; ++o) a = fmaf(bk[o], Wq[o * CC + t], a);
        w2[t] = a;
        if (t == 0) {
            float s = 0.f;
            for (int o = 0; o < CC; ++o) s = fmaf(bq[o], bk[o], s);
            s0[0] = s;
        }
    }
}

__global__ __launch_bounds__(256) void k_cvtWv(const float* __restrict__ Wv,
                                               bf16_t* __restrict__ WvB)
{
    int idx = (blockIdx.x * 256 + threadIdx.x) * 4;
    float4 v = *(const float4*)(Wv + idx);
    ushort4v h;
    h[0] = f2bf(v.x); h[1] = f2bf(v.y); h[2] = f2bf(v.z); h[3] = f2bf(v.w);
    *(ushort4v*)(WvB + idx) = h;
}

// ---------------------------------------------------------------------------
// k_tr: [b][c][m] f32 -> [b][m][c] bf16 (64x64 tiles via LDS)
// ---------------------------------------------------------------------------
__global__ __launch_bounds__(256) void k_tr(const float* __restrict__ src,
                                            bf16_t* __restrict__ dst,
                                            int Ncols, int nmt)
{
    __shared__ float s[64][65];
    const int t = threadIdx.x;
    const int per_b = 6 * nmt;
    const int b = blockIdx.x / per_b;
    const int r = blockIdx.x % per_b;
    const int ct = r / nmt, mt = r % nmt;
    const int cb = ct * 64, mbase = mt * 64;
    const float* srcb = src + (size_t)b * CC * Ncols;
    bf16_t* dstb = dst + (size_t)b * Ncols * CC;

    #pragma unroll
    for (int i = 0; i < 4; ++i) {
        int idx = i * 256 + t;
        int c_l = idx >> 4, m4 = idx & 15;
        float4 v = *(const float4*)(srcb + (size_t)(cb + c_l) * Ncols + mbase + m4 * 4);
        s[m4 * 4 + 0][c_l] = v.x; s[m4 * 4 + 1][c_l] = v.y;
        s[m4 * 4 + 2][c_l] = v.z; s[m4 * 4 + 3][c_l] = v.w;
    }
    __syncthreads();
    #pragma unroll
    for (int i = 0; i < 2; ++i) {
        int idx = i * 256 + t;
        int m_l = idx >> 3, c8 = idx & 7;
        ushort8v hv;
        #pragma unroll
        for (int j = 0; j < 8; ++j) hv[j] = f2bf(s[m_l][c8 * 8 + j]);
        *(ushort8v*)(dstb + (size_t)(mbase + m_l) * CC + cb + c8 * 8) = hv;
    }
}

// ---------------------------------------------------------------------------
// k_tvec: T[b,n] = w2 . feat[b,:,n] + s0
// ---------------------------------------------------------------------------
__global__ __launch_bounds__(256) void k_tvec(const float* __restrict__ feat,
                                              const float* __restrict__ w2,
                                              const float* __restrict__ s0,
                                              float* __restrict__ T)
{
    __shared__ float sred[256];
    const int t = threadIdx.x;
    const int b = blockIdx.x >> 6;
    const int n0 = (blockIdx.x & 63) * 32;
    const int n_l = t & 31, cp = t >> 5;
    float part = 0.f;
    for (int i = 0; i < 48; ++i) {
        int c = cp * 48 + i;
        part = fmaf(w2[c], feat[((size_t)(b * CC + c)) * NN + n0 + n_l], part);
    }
    sred[t] = part;
    __syncthreads();
    if (t < 32) {
        float s = 0.f;
        #pragma unroll
        for (int j = 0; j < 8; ++j) s += sred[j * 32 + t];
        T[b * NN + n0 + t] = s + s0[0];
    }
}

// ---------------------------------------------------------------------------
// k_u: u[b][c][n] = Mmat . feat  (GEMM) + mb[c]
// ---------------------------------------------------------------------------
__global__ __launch_bounds__(256) void k_u(const bf16_t* __restrict__ MmatB,
                                           const bf16_t* __restrict__ featT,
                                           const float* __restrict__ mb,
                                           float* __restrict__ U)
{
    __shared__ __align__(16) bf16_t sA[4096], sB[4096];
    const int mt = blockIdx.x % 3;
    const int rest = blockIdx.x / 3;
    const int nt = rest & 15, b = rest >> 4;
    f32x4 z = {0.f, 0.f, 0.f, 0.f};
    f32x4 acc[4][4];
    #pragma unroll
    for (int i = 0; i < 4; ++i)
        #pragma unroll
        for (int j = 0; j < 4; ++j) acc[i][j] = z;

    gemm128(MmatB + mt * 128 * CC, featT + ((size_t)b * NN + nt * 128) * CC, sA, sB, acc);

    const int lane = threadIdx.x & 63, w = threadIdx.x >> 6;
    const int wr = w >> 1, wc = w & 1;
    const int fr = lane & 15, fs = lane >> 4;
    #pragma unroll
    for (int mf = 0; mf < 4; ++mf) {
        int c0 = mt * 128 + wr * 64 + mf * 16 + fs * 4;
        #pragma unroll
        for (int r4 = 0; r4 < 4; ++r4) {
            float mbv = mb[c0 + r4];
            #pragma unroll
            for (int nf = 0; nf < 4; ++nf) {
                int n = nt * 128 + wc * 64 + nf * 16 + fr;
                U[((size_t)(b * CC + c0 + r4)) * NN + n] = acc[mf][nf][r4] + mbv;
            }
        }
    }
}

// ---------------------------------------------------------------------------
// k_scores: scores[b,n,k] = (u[:,n].gfT[m] + T[b,n])*SCALE, masked softmax -> P
// block = (b, group of 16 n)
// ---------------------------------------------------------------------------
__global__ __launch_bounds__(256) void k_scores(const bf16_t* __restrict__ gfT,
                                                const float* __restrict__ U,
                                                const float* __restrict__ T,
                                                const int* __restrict__ count,
                                                float* __restrict__ P)
{
    __shared__ __align__(16) float su2[16 * 384];
    __shared__ float ssc[256];
    const int t = threadIdx.x;
    const int b = blockIdx.x >> 7;
    const int nb = blockIdx.x & 127;

    for (int i = 0; i < 24; ++i) {
        int idx = i * 256 + t;
        int c = idx >> 4, n_l = idx & 15;
        su2[n_l * 384 + c] = U[((size_t)(b * CC + c)) * NN + nb * 16 + n_l];
    }
    __syncthreads();

    const int w = t >> 6, lane = t & 63;
    const int fs = lane >> 4, p = lane & 15;
    for (int j = 0; j < 16; ++j) {
        int r = j * 16 + w * 4 + fs;          // r in [0,256): n_l=r>>4, k=r&15
        const bf16_t* grow = gfT + ((size_t)(b * MM + nb * 256 + r)) * CC;
        const float* sun = su2 + (r >> 4) * 384;
        float part = 0.f;
        #pragma unroll
        for (int s = 0; s < 3; ++s) {
            int cb = (p + s * 16) * 8;
            int4v gv = *(const int4v*)(grow + cb);
            const float4* up = (const float4*)(sun + cb);
            float4 u0 = up[0], u1 = up[1];
            unsigned short* gu = (unsigned short*)&gv;
            part = fmaf(bf2f(gu[0]), u0.x, part);
            part = fmaf(bf2f(gu[1]), u0.y, part);
            part = fmaf(bf2f(gu[2]), u0.z, part);
            part = fmaf(bf2f(gu[3]), u0.w, part);
            part = fmaf(bf2f(gu[4]), u1.x, part);
            part = fmaf(bf2f(gu[5]), u1.y, part);
            part = fmaf(bf2f(gu[6]), u1.z, part);
            part = fmaf(bf2f(gu[7]), u1.w, part);
        }
        #pragma unroll
        for (int d = 1; d < 16; d <<= 1) part += __shfl_xor(part, d);
        if (p == 0) ssc[r] = part;
    }
    __syncthreads();

    {
        const int n_l = t >> 4, k = t & 15;
        float val = ssc[t];
        val = (val + T[b * NN + nb * 16 + n_l]) * SCALE;
        int cnt = count[b * NN + nb * 16 + n_l];
        cnt = cnt < 1 ? 1 : (cnt > KK ? KK : cnt);
        bool act = (k < cnt);
        float mval = act ? val : -1e30f;
        #pragma unroll
        for (int d = 1; d < 16; d <<= 1) mval = fmaxf(mval, __shfl_xor(mval, d));
        float e = act ? expf(val - mval) : 0.f;
        float ssum = e;
        #pragma unroll
        for (int d = 1; d < 16; d <<= 1) ssum += __shfl_xor(ssum, d);
        P[((size_t)(b * NN) + nb * 16 + n_l) * KK + k] = e / ssum;
    }
}

// ---------------------------------------------------------------------------
// k_stats: GEMM Wv.gf, reduce sum/sumsq per (b,o) via atomics
// ---------------------------------------------------------------------------
__global__ __launch_bounds__(256) void k_stats(const bf16_t* __restrict__ WvB,
                                               const bf16_t* __restrict__ gfT,
                                               float* __restrict__ S1,
                                               float* __restrict__ S2)
{
    __shared__ __align__(16) bf16_t sA[4096], sB[4096];
    const int mt = blockIdx.x % 3;
    const int rest = blockIdx.x / 3;
    const int nt = rest & 255, b = rest >> 8;
    f32x4 z = {0.f, 0.f, 0.f, 0.f};
    f32x4 acc[4][4];
    #pragma unroll
    for (int i = 0; i < 4; ++i)
        #pragma unroll
        for (int j = 0; j < 4; ++j) acc[i][j] = z;

    gemm128(WvB + mt * 128 * CC, gfT + ((size_t)b * MM + nt * 128) * CC, sA, sB, acc);

    const int lane = threadIdx.x & 63, w = threadIdx.x >> 6;
    const int wr = w >> 1;
    const int fr = lane & 15, fs = lane >> 4;
    #pragma unroll
    for (int mf = 0; mf < 4; ++mf) {
        int o0 = mt * 128 + wr * 64 + mf * 16 + fs * 4;
        float s1v[4] = {0.f, 0.f, 0.f, 0.f}, s2v[4] = {0.f, 0.f, 0.f, 0.f};
        #pragma unroll
        for (int nf = 0; nf < 4; ++nf)
            #pragma unroll
            for (int r4 = 0; r4 < 4; ++r4) {
                float v = acc[mf][nf][r4];
                s1v[r4] += v;
                s2v[r4] = fmaf(v, v, s2v[r4]);
            }
        #pragma unroll
        for (int r4 = 0; r4 < 4; ++r4) {
            #pragma unroll
            for (int d = 1; d < 16; d <<= 1) {
                s1v[r4] += __shfl_xor(s1v[r4], d);
                s2v[r4] += __shfl_xor(s2v[r4], d);
            }
        }
        if (fr == 0) {
            #pragma unroll
            for (int r4 = 0; r4 < 4; ++r4) {
                atomicAdd(&S1[b * CC + o0 + r4], s1v[r4]);
                atomicAdd(&S2[b * CC + o0 + r4], s2v[r4]);
            }
        }
    }
}

// ---------------------------------------------------------------------------
// k_final: alpha/beta per (b,o)
// ---------------------------------------------------------------------------
__global__ __launch_bounds__(384) void k_final(const float* __restrict__ S1,
                                               const float* __restrict__ S2,
                                               const float* __restrict__ bv,
                                               const float* __restrict__ gnw,
                                               const float* __restrict__ gnb,
                                               float* __restrict__ AB)
{
    __shared__ float smu[128], srs[128];
    const int t = threadIdx.x;
    if (t < 128) {
        int b = t >> 5, g = t & 31;
        float sv = 0.f, sv2 = 0.f;
        for (int j = 0; j < CPG; ++j) {
            int o = g * CPG + j;
            float s1 = S1[b * CC + o], s2 = S2[b * CC + o];
            float bvo = bv[o];
            sv += s1 + bvo * 32768.f;
            sv2 += s2 + 2.f * bvo * s1 + bvo * bvo * 32768.f;
        }
        const float cntf = (float)(CPG * MM);
        float mu = sv / cntf;
        float var = sv2 / cntf - mu * mu;
        smu[t] = mu;
        srs[t] = rsqrtf(var + EPSV);
    }
    __syncthreads();
    for (int pth = 0; pth < 4; ++pth) {
        int o = t, b = pth;
        int g = o / CPG;
        float a = srs[b * 32 + g] * gnw[o];
        float be = gnb[o] - smu[b * 32 + g] * a + a * bv[o];
        AB[(b * CC + o) * 2] = a;
        AB[(b * CC + o) * 2 + 1] = be;
    }
}

// ---------------------------------------------------------------------------
// k_out: GEMM Wv.gf, epilogue relu(a*acc+b)*p, k-sum via shfl, write out
// ---------------------------------------------------------------------------
__global__ __launch_bounds__(256) void k_out(const bf16_t* __restrict__ WvB,
                                             const bf16_t* __restrict__ gfT,
                                             const float* __restrict__ AB,
                                             const float* __restrict__ P,
                                             float* __restrict__ out)
{
    __shared__ __align__(16) bf16_t sA[4096], sB[4096];
    const int mt = blockIdx.x % 3;
    const int rest = blockIdx.x / 3;
    const int nt = rest & 255, b = rest >> 8;
    f32x4 z = {0.f, 0.f, 0.f, 0.f};
    f32x4 acc[4][4];
    #pragma unroll
    for (int i = 0; i < 4; ++i)
        #pragma unroll
        for (int j = 0; j < 4; ++j) acc[i][j] = z;

    gemm128(WvB + mt * 128 * CC, gfT + ((size_t)b * MM + nt * 128) * CC, sA, sB, acc);

    const int lane = threadIdx.x & 63, w = threadIdx.x >> 6;
    const int wr = w >> 1, wc = w & 1;
    const int fr = lane & 15, fs = lane >> 4;
    #pragma unroll
    for (int mf = 0; mf < 4; ++mf) {
        int o0 = mt * 128 + wr * 64 + mf * 16 + fs * 4;
        float al[4], be[4];
        #pragma unroll
        for (int r4 = 0; r4 < 4; ++r4) {
            al[r4] = AB[(b * CC + o0 + r4) * 2];
            be[r4] = AB[(b * CC + o0 + r4) * 2 + 1];
        }
        #pragma unroll
        for (int nf = 0; nf < 4; ++nf) {
            int n = nt * 8 + wc * 4 + nf;
            float pv = P[((size_t)b * NN + n) * KK + fr];
            float sum[4];
            #pragma unroll
            for (int r4 = 0; r4 < 4; ++r4) {
                float vv = fmaf(al[r4], acc[mf][nf][r4], be[r4]);
                vv = fmaxf(vv, 0.f);
                sum[r4] = pv * vv;
            }
            #pragma unroll
            for (int r4 = 0; r4 < 4; ++r4)
                #pragma unroll
                for (int d = 1; d < 16; d <<= 1) sum[r4] += __shfl_xor(sum[r4], d);
            if (fr == 0) {
                #pragma unroll
                for (int r4 = 0; r4 < 4; ++r4)
                    out[((size_t)(b * CC + o0 + r4)) * NN + n] = 16.f * sum[r4];
            }
        }
    }
}

// ===========================================================================
// FALLBACK (round-1 fp32 path) — used when ws_size is too small
// ===========================================================================
#define WS_STATS 0
#define WS_AB    256
#define WS_P     3328

__global__ __launch_bounds__(384) void k_qscore_stats(
    const float* __restrict__ feat, const float* __restrict__ gf,
    const int* __restrict__ count,
    const float* __restrict__ Wq, const float* __restrict__ bq,
    const float* __restrict__ Wk, const float* __restrict__ bk,
    const float* __restrict__ Wv, const float* __restrict__ bv,
    float* __restrict__ stats, float* __restrict__ p_out)
{
    const int bid = blockIdx.x;
    const int b = bid >> 11;
    const int n = bid & (NN - 1);
    const int tid = threadIdx.x;

    __shared__ float sf[CC];
    __shared__ float sq[CC];
    __shared__ float su[CC];
    __shared__ float sg[CC * KK];
    __shared__ float red1[CC];
    __shared__ float red2[CC];
    __shared__ float sp[KK];
    __shared__ float s_qb;

    sf[tid] = feat[(size_t)b * CC * NN + (size_t)tid * NN + n];
    {
        const float4* gf4 = reinterpret_cast<const float4*>(
            gf + (size_t)b * CC * NN * KK + (size_t)n * KK);
        float4* sg4 = reinterpret_cast<float4*>(sg);
        for (int idx = tid; idx < CC * 4; idx += 384) {
            int c = idx >> 2, j = idx & 3;
            sg4[idx] = gf4[(size_t)c * (NN * KK / 4) + j];
        }
    }
    __syncthreads();

    float qo = bq[tid];
    {
        const float4* wq4 = reinterpret_cast<const float4*>(Wq + (size_t)tid * CC);
        const float4* sf4 = reinterpret_cast<const float4*>(sf);
        #pragma unroll 8
        for (int c4 = 0; c4 < CC / 4; ++c4) {
            float4 w = wq4[c4]; float4 f = sf4[c4];
            qo = fmaf(w.x, f.x, qo); qo = fmaf(w.y, f.y, qo);
            qo = fmaf(w.z, f.z, qo); qo = fmaf(w.w, f.w, qo);
        }
    }
    sq[tid] = qo;
    red1[tid] = qo * bk[tid];
    __syncthreads();
    for (int s = 192; s > 1; s >>= 1) {
        if (tid < s) red1[tid] += red1[tid + s];
        __syncthreads();
    }
    if (tid == 0) s_qb = red1[0] + red1[1] + red1[2];
    __syncthreads();
    {
        float uc = 0.f;
        #pragma unroll 8
        for (int o = 0; o < CC; ++o)
            uc = fmaf(sq[o], Wk[(size_t)o * CC + tid], uc);
        su[tid] = uc;
    }
    __syncthreads();
    {
        int k = tid & 15, ch = tid >> 4;
        float part = 0.f;
        for (int c = ch * 16; c < ch * 16 + 16; ++c)
            part = fmaf(su[c], sg[(c << 4) + k], part);
        red2[tid] = part;
    }
    __syncthreads();
    if (tid < KK) {
        float s = 0.f;
        for (int j = 0; j < 24; ++j) s += red2[tid + 16 * j];
        sp[tid] = (s + s_qb) * SCALE;
    }
    __syncthreads();
    if (tid == 0) {
        int cnt = count[b * NN + n];
        if (cnt < 1) cnt = 1; if (cnt > KK) cnt = KK;
        float m = -1e30f;
        for (int k = 0; k < cnt; ++k) m = fmaxf(m, sp[k]);
        float ssum = 0.f;
        float e[KK];
        for (int k = 0; k < KK; ++k) {
            e[k] = (k < cnt) ? expf(sp[k] - m) : 0.f;
            ssum += e[k];
        }
        float inv = 1.f / ssum;
        for (int k = 0; k < KK; ++k)
            p_out[((size_t)b * NN + n) * KK + k] = e[k] * inv;
    }

    float accv[KK];
    #pragma unroll
    for (int k = 0; k < KK; ++k) accv[k] = 0.f;
    {
        const float* wv = Wv + (size_t)tid * CC;
        for (int c = 0; c < CC; ++c) {
            float wgt = wv[c];
            const float4* row = reinterpret_cast<const float4*>(sg + (c << 4));
            float4 a0 = row[0], a1 = row[1], a2 = row[2], a3 = row[3];
            accv[0]  = fmaf(wgt, a0.x, accv[0]);  accv[1]  = fmaf(wgt, a0.y, accv[1]);
            accv[2]  = fmaf(wgt, a0.z, accv[2]);  accv[3]  = fmaf(wgt, a0.w, accv[3]);
            accv[4]  = fmaf(wgt, a1.x, accv[4]);  accv[5]  = fmaf(wgt, a1.y, accv[5]);
            accv[6]  = fmaf(wgt, a1.z, accv[6]);  accv[7]  = fmaf(wgt, a1.w, accv[7]);
            accv[8]  = fmaf(wgt, a2.x, accv[8]);  accv[9]  = fmaf(wgt, a2.y, accv[9]);
            accv[10] = fmaf(wgt, a2.z, accv[10]); accv[11] = fmaf(wgt, a2.w, accv[11]);
            accv[12] = fmaf(wgt, a3.x, accv[12]); accv[13] = fmaf(wgt, a3.y, accv[13]);
            accv[14] = fmaf(wgt, a3.z, accv[14]); accv[15] = fmaf(wgt, a3.w, accv[15]);
        }
    }
    {
        float bvo = bv[tid];
        float s1 = 0.f, s2 = 0.f;
        #pragma unroll
        for (int k = 0; k < KK; ++k) {
            float v = accv[k] + bvo;
            s1 += v; s2 = fmaf(v, v, s2);
        }
        __syncthreads();
        red1[tid] = s1; red2[tid] = s2;
    }
    __syncthreads();
    if (tid < GG) {
        float a1 = 0.f, a2 = 0.f;
        for (int j = 0; j < CPG; ++j) {
            a1 += red1[tid * CPG + j];
            a2 += red2[tid * CPG + j];
        }
        atomicAdd(&stats[(b * GG + tid) * 2 + 0], a1);
        atomicAdd(&stats[(b * GG + tid) * 2 + 1], a2);
    }
}

__global__ __launch_bounds__(384) void k_stats_final(
    const float* __restrict__ stats,
    const float* __restrict__ gn_w, const float* __restrict__ gn_b,
    const float* __restrict__ bv, float* __restrict__ ab)
{
    __shared__ float smu[BB * GG], srs[BB * GG];
    int tid = threadIdx.x;
    if (tid < BB * GG) {
        float s1 = stats[tid * 2], s2 = stats[tid * 2 + 1];
        const float cnt = (float)(CPG * NN * KK);
        float mu = s1 / cnt;
        float var = s2 / cnt - mu * mu;
        smu[tid] = mu;
        srs[tid] = rsqrtf(var + EPSV);
    }
    __syncthreads();
    for (int i = tid; i < BB * CC; i += 384) {
        int b = i / CC, o = i % CC;
        int g = o / CPG;
        float rs = srs[b * GG + g], mu = smu[b * GG + g];
        float a = rs * gn_w[o];
        float be = gn_b[o] - mu * a + a * bv[o];
        ab[i * 2] = a;
        ab[i * 2 + 1] = be;
    }
}

__global__ __launch_bounds__(384) void k_out_fb(
    const float* __restrict__ gf, const float* __restrict__ Wv,
    const float* __restrict__ ab, const float* __restrict__ p_in,
    float* __restrict__ out)
{
    const int bid = blockIdx.x;
    const int b = bid >> 11;
    const int n = bid & (NN - 1);
    const int tid = threadIdx.x;

    __shared__ float sg[CC * KK];
    __shared__ float sp[KK];

    {
        const float4* gf4 = reinterpret_cast<const float4*>(
            gf + (size_t)b * CC * NN * KK + (size_t)n * KK);
        float4* sg4 = reinterpret_cast<float4*>(sg);
        for (int idx = tid; idx < CC * 4; idx += 384) {
            int c = idx >> 2, j = idx & 3;
            sg4[idx] = gf4[(size_t)c * (NN * KK / 4) + j];
        }
    }
    if (tid < KK) sp[tid] = p_in[((size_t)b * NN + n) * KK + tid];
    __syncthreads();

    float accv[KK];
    #pragma unroll
    for (int k = 0; k < KK; ++k) accv[k] = 0.f;
    {
        const float* wv = Wv + (size_t)tid * CC;
        for (int c = 0; c < CC; ++c) {
            float wgt = wv[c];
            const float4* row = reinterpret_cast<const float4*>(sg + (c << 4));
            float4 a0 = row[0], a1 = row[1], a2 = row[2], a3 = row[3];
            accv[0]  = fmaf(wgt, a0.x, accv[0]);  accv[1]  = fmaf(wgt, a0.y, accv[1]);
            accv[2]  = fmaf(wgt, a0.z, accv[2]);  accv[3]  = fmaf(wgt, a0.w, accv[3]);
            accv[4]  = fmaf(wgt, a1.x, accv[4]);  accv[5]  = fmaf(wgt, a1.y, accv[5]);
            accv[6]  = fmaf(wgt, a1.z, accv[6]);  accv[7]  = fmaf(wgt, a1.w, accv[7]);
            accv[8]  = fmaf(wgt, a2.x, accv[8]);  accv[9]  = fmaf(wgt, a2.y, accv[9]);
            accv[10] = fmaf(wgt, a2.z, accv[10]); accv[11] = fmaf(wgt, a2.w, accv[11]);
            accv[12] = fmaf(wgt, a3.x, accv[12]); accv[13] = fmaf(wgt, a3.y, accv[13]);
            accv[14] = fmaf(wgt, a3.z, accv[14]); accv[15] = fmaf(wgt, a3.w, accv[15]);
        }
    }
    const float a  = ab[((size_t)b * CC + tid) * 2];
    const float be = ab[((size_t)b * CC + tid) * 2 + 1];
    float ov = 0.f;
    #pragma unroll
    for (int k = 0; k < KK; ++k) {
        float vn = fmaf(a, accv[k], be);
        vn = fmaxf(vn, 0.f);
        ov = fmaf(sp[k], vn, ov);
    }
    out[(size_t)b * CC * NN + (size_t)tid * NN + n] = 16.f * ov;
}

// ===========================================================================
extern "C" void kernel_launch(void* const* d_in, const int* in_sizes, int n_in,
                              void* d_out, int out_size, void* d_ws, size_t ws_size,
                              hipStream_t stream) {
    const float* feat = (const float*)d_in[0];
    const float* gf   = (const float*)d_in[1];
    const int*   cnt  = (const int*)d_in[2];
    const float* Wq   = (const float*)d_in[3];
    const float* bq   = (const float*)d_in[4];
    const float* Wk   = (const float*)d_in[5];
    const float* bk   = (const float*)d_in[6];
    const float* Wv   = (const float*)d_in[7];
    const float* bv   = (const float*)d_in[8];
    const float* gnw  = (const float*)d_in[9];
    const float* gnb  = (const float*)d_in[10];
    float* out = (float*)d_out;

    // ws layout (bytes, 256-aligned)
    size_t off = 0;
    auto alloc = [&off](size_t bytes) {
        size_t o = off;
        off = (off + bytes + 255) & ~(size_t)255;
        return o;
    };
    size_t oM  = alloc(294912);                 // Mmat bf16
    size_t oWv = alloc(294912);                 // Wv bf16
    size_t oFT = alloc((size_t)BB * NN * CC * 2);     // featT bf16
    size_t oGT = alloc((size_t)BB * MM * CC * 2);     // gfT bf16
    size_t oU  = alloc((size_t)BB * CC * NN * 4);     // u f32
    size_t oT  = alloc((size_t)BB * NN * 4);          // t f32
    size_t oS  = alloc(2 * (size_t)BB * CC * 4);      // S1+S2
    size_t oAB = alloc((size_t)BB * CC * 2 * 4);      // alpha/beta
    size_t oP  = alloc((size_t)BB * NN * KK * 4);     // softmax probs
    size_t oW2 = alloc(CC * 4);
    size_t oS0 = alloc(256);
    size_t oMB = alloc(CC * 4);
    size_t need = off;

    char* w = (char*)d_ws;
    if (ws_size >= need) {
        bf16_t* MmatB = (bf16_t*)(w + oM);
        bf16_t* WvB   = (bf16_t*)(w + oWv);
        bf16_t* featT = (bf16_t*)(w + oFT);
        bf16_t* gfT   = (bf16_t*)(w + oGT);
        float* U   = (float*)(w + oU);
        float* T   = (float*)(w + oT);
        float* S1  = (float*)(w + oS);
        float* S2  = S1 + BB * CC;
        float* AB  = (float*)(w + oAB);
        float* P   = (float*)(w + oP);
        float* w2  = (float*)(w + oW2);
        float* s0  = (float*)(w + oS0);
        float* mb  = (float*)(w + oMB);

        hipMemsetAsync(S1, 0, 2 * BB * CC * sizeof(float), stream);
        k_prep<<<385, 384, 0, stream>>>(Wq, Wk, bq, bk, MmatB, w2, s0, mb);
        k_cvtWv<<<144, 256, 0, stream>>>(Wv, WvB);
        k_tr<<<BB * 6 * (NN / 64), 256, 0, stream>>>(feat, featT, NN, NN / 64);
        k_tr<<<BB * 6 * (MM / 64), 256, 0, stream>>>(gf, gfT, MM, MM / 64);
        k_tvec<<<BB * (NN / 32), 256, 0, stream>>>(feat, w2, s0, T);
        k_u<<<3 * 16 * BB, 256, 0, stream>>>(MmatB, featT, mb, U);
        k_scores<<<BB * 128, 256, 0, stream>>>(gfT, U, T, cnt, P);
        k_stats<<<3 * 256 * BB, 256, 0, stream>>>(WvB, gfT, S1, S2);
        k_final<<<1, 384, 0, stream>>>(S1, S2, bv, gnw, gnb, AB);
        k_out<<<3 * 256 * BB, 256, 0, stream>>>(WvB, gfT, AB, P, out);
    } else {
        float* ws = (float*)d_ws;
        float* stats = ws + WS_STATS;
        float* ab    = ws + WS_AB;
        float* p     = ws + WS_P;
        hipMemsetAsync(stats, 0, 256 * sizeof(float), stream);
        k_qscore_stats<<<BB * NN, 384, 0, stream>>>(feat, gf, cnt, Wq, bq, Wk, bk,
                                                    Wv, bv, stats, p);
        k_stats_final<<<1, 384, 0, stream>>>(stats, gnw, gnb, bv, ab);
        k_out_fb<<<BB * NN, 384, 0, stream>>>(gf, Wv, ab, p, out);
    }
}